// Round 1
// baseline (527.852 us; speedup 1.0000x reference)
//
#include <hip/hip_runtime.h>
#include <math.h>

#define LEAKY(x) ((x) >= 0.f ? (x) : 0.3f*(x))

// ---- workspace float offsets ----
#define G_OFF   0         // 648     extracted g~ (72x9)
#define IM_OFF  648       // 7776    im (b,ch,81)
#define LAM_OFF 8424      // 32      lambda per batch
#define WB_OFF  8456      // 2592    w branch (b,81)
#define YBR_OFF 11048     // 82944   y branch (b,81,32)
#define X1_OFF  93992     // 663552  conv51 out (b,36,36,16)
#define X2_OFF  757544    // 331776  conv15 out (b,18,18,32)
#define X3_OFF  1089320   // 165888  conv55 out (b,9,9,64)

#define OUT0 106272       // elements in output 0; cs_out follows

// ======================= prep =======================
__global__ __launch_bounds__(256) void prep_kernel(
    const float* __restrict__ inp, const float* __restrict__ mat,
    const float* __restrict__ w1_k, const float* __restrict__ w1_b,
    const float* __restrict__ x1_k, const float* __restrict__ x1_b,
    const float* __restrict__ y17_k, const float* __restrict__ y17_b,
    const float* __restrict__ y71_k, const float* __restrict__ y71_b,
    const float* __restrict__ yc_k, const float* __restrict__ yc_b,
    const float* __restrict__ d1_k, const float* __restrict__ d2_k,
    const float* __restrict__ h1_w, const float* __restrict__ h1_b,
    const float* __restrict__ h2_w, const float* __restrict__ h2_b,
    const float* __restrict__ h3_w, const float* __restrict__ h3_b,
    float* __restrict__ ws)
{
    int t = threadIdx.x;
    if (blockIdx.x == 0) {
        // extract separable factor: g[i][a] = mat[i*72, a*9] / sqrt(mat[0,0])
        float rs = rsqrtf(mat[0]);
        for (int u = t; u < 648; u += 256) {
            int i = u / 9, a = u % 9;
            ws[G_OFF + u] = mat[(size_t)(i*72)*81 + a*9] * rs;
        }
        return;
    }
    int b = blockIdx.x - 1;
    __shared__ float sin_[243];
    __shared__ float cm[27];
    __shared__ float cat[5184];
    __shared__ float z1[108];
    __shared__ float z2[24];
    __shared__ float v1[24];
    __shared__ float v2[12];

    const float BN  = 1.0f / sqrtf(1.001f);
    const float BN2 = BN * BN;

    for (int u = t; u < 243; u += 256) sin_[u] = inp[b*243 + u];
    __syncthreads();

    // w branch (t<81), colmax (81..107), d1 conv (128..235)
    if (t < 81) {
        float s = w1_b[0];
        for (int i = 0; i < 3; ++i) s += sin_[t*3+i] * w1_k[i];
        ws[WB_OFF + b*81 + t] = LEAKY(s);
    } else if (t < 108) {
        int u = t - 81;                       // c*3+ch
        float m = 0.f;
        for (int r = 0; r < 9; ++r) m = fmaxf(m, fabsf(sin_[r*27 + u]));
        cm[u] = 0.001f + m;
    }
    if (t >= 128 && t < 236) {
        int u = t - 128;                      // oy*36 + ox*12 + o
        int o = u % 12, ox = (u/12) % 3, oy = u/36;
        float s = 0.f;
        for (int kh = 0; kh < 5; ++kh) {
            int iy = oy*3 - 1 + kh;
            if (iy < 0 || iy > 8) continue;
            for (int kw = 0; kw < 5; ++kw) {
                int ix = ox*3 - 1 + kw;
                if (ix < 0 || ix > 8) continue;
                for (int i = 0; i < 3; ++i)
                    s += sin_[(iy*9+ix)*3 + i] * d1_k[((kh*5+kw)*3 + i)*12 + o];
            }
        }
        z1[u] = LEAKY(BN2 * s);
    }
    __syncthreads();

    // im = leaky(conv1x1(inp / colmax)) ; layout (b,ch,81)
    if (t < 243) {
        int o = t / 81, p = t % 81;
        int c = p % 9;
        float s = x1_b[o];
        for (int i = 0; i < 3; ++i)
            s += (sin_[p*3+i] / cm[c*3+i]) * x1_k[i*3 + o];
        ws[IM_OFF + (b*3 + o)*81 + p] = LEAKY(s);
    }
    __syncthreads();

    // d2 conv: 3x3x12 -> 1x1x24 (kernel rows/cols 1..3 valid)
    if (t < 24) {
        float s = 0.f;
        for (int kh = 1; kh < 4; ++kh)
            for (int kw = 1; kw < 4; ++kw)
                for (int i = 0; i < 12; ++i)
                    s += z1[((kh-1)*3 + (kw-1))*12 + i] * d2_k[((kh*5+kw)*12 + i)*24 + t];
        z2[t] = LEAKY(BN * s);
    }
    __syncthreads();
    if (t < 24) {
        float s = h1_b[t];
        for (int i = 0; i < 24; ++i) s += z2[i] * h1_w[i*24 + t];
        v1[t] = s;
    }
    __syncthreads();
    if (t < 12) {
        float s = h2_b[t];
        for (int i = 0; i < 24; ++i) s += v1[i] * h2_w[i*12 + t];
        v2[t] = s;
    }
    __syncthreads();
    if (t == 0) {
        float s = h3_b[0];
        for (int i = 0; i < 12; ++i) s += v2[i] * h3_w[i];
        ws[LAM_OFF + b] = 0.01f / (1.f + expf(-s));   // 0.1*sigmoid * 0.1
    }

    // y branch: cat = [y1(32) | y2(32)] per position
    for (int u = t; u < 5184; u += 256) {
        int pos = u / 64, i = u % 64;
        int r = pos / 9, c = pos % 9;
        float s;
        if (i < 32) {
            s = y17_b[i];
            for (int kw = 0; kw < 7; ++kw) {
                int cc = c - 3 + kw;
                if (cc < 0 || cc > 8) continue;
                for (int ii = 0; ii < 3; ++ii)
                    s += sin_[(r*9+cc)*3 + ii] * y17_k[(kw*3+ii)*32 + i];
            }
        } else {
            int i2 = i - 32;
            s = y71_b[i2];
            for (int kh = 0; kh < 7; ++kh) {
                int rr = r - 3 + kh;
                if (rr < 0 || rr > 8) continue;
                for (int ii = 0; ii < 3; ++ii)
                    s += sin_[(rr*9+c)*3 + ii] * y71_k[(kh*3+ii)*32 + i2];
            }
        }
        cat[pos*64 + i] = s;
    }
    __syncthreads();
    for (int u = t; u < 2592; u += 256) {
        int pos = u / 32, o = u % 32;
        float s = yc_b[o];
        for (int i = 0; i < 64; ++i) s += cat[pos*64 + i] * yc_k[i*32 + o];
        ws[YBR_OFF + (b*81 + pos)*32 + o] = LEAKY(s);
    }
}

// ======================= FISTA =======================
// One block per (b,ch). y_tmp/y_last live in registers: thread (j, grp)
// owns column j, rows grp*12..grp*12+11.  432 active threads of 512.
#define USTR 436
__global__ __launch_bounds__(512) void fista_kernel(
    const float* __restrict__ ws, float* __restrict__ cs_out)
{
    __shared__ __align__(16) float Gs[864];       // g padded [i][12]
    __shared__ __align__(16) float GT[648];       // g^T [b][72]
    __shared__ __align__(16) float U[9*USTR];     // A-partials [a][grp*72+j]
    __shared__ __align__(16) float Qt[648];       // Q^T [a][72]
    __shared__ __align__(16) float R[108];        // resid padded [a][12]

    int t = threadIdx.x;
    int blk = blockIdx.x;
    int b = blk / 3, ch = blk % 3;
    const float* g = ws + G_OFF;
    float lam = ws[LAM_OFF + b];

    for (int u = t; u < 864; u += 512) { int i = u/12, a = u%12; Gs[u] = (a < 9) ? g[i*9+a] : 0.f; }
    for (int u = t; u < 648; u += 512) { int bb = u/72, j = u%72; GT[u] = g[j*9+bb]; }
    if (t < 108 && (t % 12) >= 9) R[t] = 0.f;                 // pads only
    float im_ab = 0.f;
    if (t < 81) {
        im_ab = ws[IM_OFF + (b*3 + ch)*81 + t];
        R[(t/9)*12 + (t%9)] = im_ab;                          // resid(y=0) = im
    }
    int j = t % 72, grp = t / 72;
    bool act = t < 432;
    float Yv[12], Yl[12];
#pragma unroll
    for (int s = 0; s < 12; ++s) { Yv[s] = 0.f; Yl[s] = 0.f; }
    float tk = 1.f;
    __syncthreads();

    for (int it = 0; it < 100; ++it) {
        // C': Qt[a][j] = dot(R row a, g row j)   (pads are zero)
        for (int o = t; o < 648; o += 512) {
            int a = o / 72, jj = o % 72;
            const float4* R4 = (const float4*)(R + a*12);
            const float4* G4 = (const float4*)(Gs + jj*12);
            float4 r0 = R4[0], r1 = R4[1], r2 = R4[2];
            float4 g0 = G4[0], g1 = G4[1], g2 = G4[2];
            Qt[o] = r0.x*g0.x + r0.y*g0.y + r0.z*g0.z + r0.w*g0.w
                  + r1.x*g1.x + r1.y*g1.y + r1.z*g1.z + r1.w*g1.w
                  + r2.x*g2.x + r2.y*g2.y + r2.z*g2.z + r2.w*g2.w;
        }
        __syncthreads();
        float tn = 0.5f*(1.f + sqrtf(1.f + 4.f*tk*tk));
        float cmom = (tk - 1.f) / tn;
        tk = tn;
        if (act) {
            float q0 = Qt[0*72+j], q1 = Qt[1*72+j], q2 = Qt[2*72+j],
                  q3 = Qt[3*72+j], q4 = Qt[4*72+j], q5 = Qt[5*72+j],
                  q6 = Qt[6*72+j], q7 = Qt[7*72+j], q8 = Qt[8*72+j];
            float u0=0,u1=0,u2=0,u3=0,u4=0,u5=0,u6=0,u7=0,u8=0;
#pragma unroll
            for (int s = 0; s < 12; ++s) {
                const float4* G4 = (const float4*)(Gs + (grp*12 + s)*12);
                float4 ga = G4[0], gb = G4[1], gc = G4[2];
                float re = ga.x*q0 + ga.y*q1 + ga.z*q2 + ga.w*q3
                         + gb.x*q4 + gb.y*q5 + gb.z*q6 + gb.w*q7 + gc.x*q8;
                float wv = Yv[s] + re;
                float aa = fabsf(wv) - lam;
                float yn = aa > 0.f ? copysignf(aa, wv) : 0.f;
                float yx = yn + cmom*(yn - Yl[s]);
                Yl[s] = yn; Yv[s] = yx;
                u0 += yx*ga.x; u1 += yx*ga.y; u2 += yx*ga.z; u3 += yx*ga.w;
                u4 += yx*gb.x; u5 += yx*gb.y; u6 += yx*gb.z; u7 += yx*gb.w;
                u8 += yx*gc.x;
            }
            U[0*USTR+t]=u0; U[1*USTR+t]=u1; U[2*USTR+t]=u2; U[3*USTR+t]=u3;
            U[4*USTR+t]=u4; U[5*USTR+t]=u5; U[6*USTR+t]=u6; U[7*USTR+t]=u7;
            U[8*USTR+t]=u8;
        }
        if (it == 99) break;
        __syncthreads();
        // B': S[a][b] = sum_j T[a][j]*g[j][b]; R = im - S
        if (t < 81) {
            int a = t/9, bb = t%9;
            const float* Ub = U + a*USTR;
            const float4* GT4 = (const float4*)(GT + bb*72);
            float s = 0.f;
            for (int jq = 0; jq < 18; ++jq) {
                float4 w0 = ((const float4*)(Ub      ))[jq];
                float4 w1 = ((const float4*)(Ub +  72))[jq];
                float4 w2 = ((const float4*)(Ub + 144))[jq];
                float4 w3 = ((const float4*)(Ub + 216))[jq];
                float4 w4 = ((const float4*)(Ub + 288))[jq];
                float4 w5 = ((const float4*)(Ub + 360))[jq];
                float sx = w0.x+w1.x+w2.x+w3.x+w4.x+w5.x;
                float sy = w0.y+w1.y+w2.y+w3.y+w4.y+w5.y;
                float sz = w0.z+w1.z+w2.z+w3.z+w4.z+w5.z;
                float sw = w0.w+w1.w+w2.w+w3.w+w4.w+w5.w;
                float4 gt = GT4[jq];
                s += sx*gt.x + sy*gt.y + sz*gt.z + sw*gt.w;
            }
            R[a*12 + bb] = im_ab - s;
        }
        __syncthreads();
    }
    if (act) {
#pragma unroll
        for (int s = 0; s < 12; ++s) {
            int i = grp*12 + s;
            cs_out[(size_t)(b*5184 + i*72 + j)*3 + ch] = Yl[s];
        }
    }
}

// ======================= post convs =======================
__global__ __launch_bounds__(256) void c51_kernel(
    const float* __restrict__ cs, const float* __restrict__ k,
    const float* __restrict__ bias, float* __restrict__ out)
{
    int id = blockIdx.x*256 + threadIdx.x;
    if (id >= 32*36*36*16) return;
    int o = id & 15; int rest = id >> 4;
    int ox = rest % 36; rest /= 36; int oy = rest % 36; int b = rest / 36;
    float s = bias[o];
    int ix = ox*2;
    for (int kh = 0; kh < 5; ++kh) {
        int iy = oy*2 - 1 + kh;
        if (iy < 0 || iy >= 72) continue;
        const float* p = cs + ((size_t)(b*72 + iy)*72 + ix)*3;
        const float* kk = k + kh*48 + o;
        s += p[0]*kk[0] + p[1]*kk[16] + p[2]*kk[32];
    }
    out[id] = s;
}

__global__ __launch_bounds__(256) void c15_kernel(
    const float* __restrict__ x1, const float* __restrict__ k,
    const float* __restrict__ bias, float* __restrict__ out)
{
    int id = blockIdx.x*256 + threadIdx.x;
    if (id >= 32*18*18*32) return;
    int o = id & 31; int rest = id >> 5;
    int ox = rest % 18; rest /= 18; int oy = rest % 18; int b = rest / 18;
    float s = bias[o];
    int iy = oy*2;
    for (int kw = 0; kw < 5; ++kw) {
        int ix = ox*2 - 1 + kw;
        if (ix < 0 || ix >= 36) continue;
        const float* p = x1 + ((size_t)(b*36 + iy)*36 + ix)*16;
        const float* kk = k + kw*512 + o;
        for (int i = 0; i < 16; ++i) s += p[i]*kk[i*32];
    }
    out[id] = s;
}

__global__ __launch_bounds__(256) void c55_kernel(
    const float* __restrict__ x2, const float* __restrict__ k,
    const float* __restrict__ bias, float* __restrict__ out)
{
    int id = blockIdx.x*256 + threadIdx.x;
    if (id >= 32*9*9*64) return;
    int o = id & 63; int rest = id >> 6;
    int ox = rest % 9; rest /= 9; int oy = rest % 9; int b = rest / 9;
    float s = bias[o];
    for (int kh = 0; kh < 5; ++kh) {
        int iy = oy*2 - 1 + kh;
        if (iy < 0 || iy >= 18) continue;
        for (int kw = 0; kw < 5; ++kw) {
            int ix = ox*2 - 1 + kw;
            if (ix < 0 || ix >= 18) continue;
            const float* p = x2 + ((size_t)(b*18 + iy)*18 + ix)*32;
            const float* kk = k + (kh*5+kw)*2048 + o;
            for (int i = 0; i < 32; ++i) s += p[i]*kk[i*64];
        }
    }
    out[id] = s;
}

__global__ __launch_bounds__(256) void out_kernel(
    const float* __restrict__ ws, const float* __restrict__ x2_k,
    const float* __restrict__ x2_b, float* __restrict__ out)
{
    int id = blockIdx.x*256 + threadIdx.x;
    if (id >= OUT0) return;
    int q = id % 41; int rest = id / 41;
    int cc = rest % 9; rest /= 9; int r = rest % 9; int b = rest / 9;
    float val;
    if (q == 0) {
        val = ws[WB_OFF + b*81 + r*9 + cc];
    } else if (q <= 8) {
        int o = q - 1;
        const float* p = ws + X3_OFF + ((size_t)(b*9 + r)*9 + cc)*64;
        float s = x2_b[o];
        for (int i = 0; i < 64; ++i) s += p[i]*x2_k[i*8 + o];
        val = LEAKY(s);
    } else {
        val = ws[YBR_OFF + ((size_t)(b*81 + r*9 + cc))*32 + (q - 9)];
    }
    out[id] = val;
}

// ======================= launch =======================
extern "C" void kernel_launch(void* const* d_in, const int* in_sizes, int n_in,
                              void* d_out, int out_size, void* d_ws, size_t ws_size,
                              hipStream_t stream) {
    const float* inp   = (const float*)d_in[0];
    const float* mat   = (const float*)d_in[1];
    const float* w1_k  = (const float*)d_in[2];
    const float* w1_b  = (const float*)d_in[3];
    const float* x1_k  = (const float*)d_in[4];
    const float* x1_b  = (const float*)d_in[5];
    const float* c51_k = (const float*)d_in[6];
    const float* c51_b = (const float*)d_in[7];
    const float* c15_k = (const float*)d_in[8];
    const float* c15_b = (const float*)d_in[9];
    const float* c55_k = (const float*)d_in[10];
    const float* c55_b = (const float*)d_in[11];
    const float* x2_k  = (const float*)d_in[12];
    const float* x2_b  = (const float*)d_in[13];
    const float* y17_k = (const float*)d_in[14];
    const float* y17_b = (const float*)d_in[15];
    const float* y71_k = (const float*)d_in[16];
    const float* y71_b = (const float*)d_in[17];
    const float* yc_k  = (const float*)d_in[18];
    const float* yc_b  = (const float*)d_in[19];
    const float* d1_k  = (const float*)d_in[20];
    const float* d2_k  = (const float*)d_in[21];
    const float* h1_w  = (const float*)d_in[22];
    const float* h1_b  = (const float*)d_in[23];
    const float* h2_w  = (const float*)d_in[24];
    const float* h2_b  = (const float*)d_in[25];
    const float* h3_w  = (const float*)d_in[26];
    const float* h3_b  = (const float*)d_in[27];

    float* ws  = (float*)d_ws;
    float* out = (float*)d_out;
    float* cs  = out + OUT0;

    hipLaunchKernelGGL(prep_kernel, dim3(33), dim3(256), 0, stream,
        inp, mat, w1_k, w1_b, x1_k, x1_b, y17_k, y17_b, y71_k, y71_b,
        yc_k, yc_b, d1_k, d2_k, h1_w, h1_b, h2_w, h2_b, h3_w, h3_b, ws);
    hipLaunchKernelGGL(fista_kernel, dim3(96), dim3(512), 0, stream, ws, cs);
    hipLaunchKernelGGL(c51_kernel, dim3(2592), dim3(256), 0, stream, cs, c51_k, c51_b, ws + X1_OFF);
    hipLaunchKernelGGL(c15_kernel, dim3(1296), dim3(256), 0, stream, ws + X1_OFF, c15_k, c15_b, ws + X2_OFF);
    hipLaunchKernelGGL(c55_kernel, dim3(648), dim3(256), 0, stream, ws + X2_OFF, c55_k, c55_b, ws + X3_OFF);
    hipLaunchKernelGGL(out_kernel, dim3(416), dim3(256), 0, stream, ws, x2_k, x2_b, out);
}

// Round 2
// 399.458 us; speedup vs baseline: 1.3214x; 1.3214x over previous
//
#include <hip/hip_runtime.h>
#include <math.h>

#define LEAKY(x) ((x) >= 0.f ? (x) : 0.3f*(x))

// ---- workspace float offsets ----
#define G_OFF   0         // 648     extracted g~ (72x9)
#define IM_OFF  648       // 7776    im (b,ch,81)
#define LAM_OFF 8424      // 32      lambda per batch
#define WB_OFF  8456      // 2592    w branch (b,81)
#define YBR_OFF 11048     // 82944   y branch (b,81,32)
#define X1_OFF  93992     // 663552  conv51 out (b,36,36,16)
#define X2_OFF  757544    // 331776  conv15 out (b,18,18,32)
#define X3_OFF  1089320   // 165888  conv55 out (b,9,9,64)

#define OUT0 106272       // elements in output 0; cs_out follows

// ======================= prep =======================
__global__ __launch_bounds__(256) void prep_kernel(
    const float* __restrict__ inp, const float* __restrict__ mat,
    const float* __restrict__ w1_k, const float* __restrict__ w1_b,
    const float* __restrict__ x1_k, const float* __restrict__ x1_b,
    const float* __restrict__ y17_k, const float* __restrict__ y17_b,
    const float* __restrict__ y71_k, const float* __restrict__ y71_b,
    const float* __restrict__ yc_k, const float* __restrict__ yc_b,
    const float* __restrict__ d1_k, const float* __restrict__ d2_k,
    const float* __restrict__ h1_w, const float* __restrict__ h1_b,
    const float* __restrict__ h2_w, const float* __restrict__ h2_b,
    const float* __restrict__ h3_w, const float* __restrict__ h3_b,
    float* __restrict__ ws)
{
    int t = threadIdx.x;
    if (blockIdx.x == 0) {
        // extract separable factor: g[i][a] = mat[i*72, a*9] / sqrt(mat[0,0])
        float rs = rsqrtf(mat[0]);
        for (int u = t; u < 648; u += 256) {
            int i = u / 9, a = u % 9;
            ws[G_OFF + u] = mat[(size_t)(i*72)*81 + a*9] * rs;
        }
        return;
    }
    int b = blockIdx.x - 1;
    __shared__ float sin_[243];
    __shared__ float cm[27];
    __shared__ float cat[5184];
    __shared__ float z1[108];
    __shared__ float z2[24];
    __shared__ float v1[24];
    __shared__ float v2[12];

    const float BN  = 1.0f / sqrtf(1.001f);
    const float BN2 = BN * BN;

    for (int u = t; u < 243; u += 256) sin_[u] = inp[b*243 + u];
    __syncthreads();

    // w branch (t<81), colmax (81..107), d1 conv (128..235)
    if (t < 81) {
        float s = w1_b[0];
        for (int i = 0; i < 3; ++i) s += sin_[t*3+i] * w1_k[i];
        ws[WB_OFF + b*81 + t] = LEAKY(s);
    } else if (t < 108) {
        int u = t - 81;                       // c*3+ch
        float m = 0.f;
        for (int r = 0; r < 9; ++r) m = fmaxf(m, fabsf(sin_[r*27 + u]));
        cm[u] = 0.001f + m;
    }
    if (t >= 128 && t < 236) {
        int u = t - 128;                      // oy*36 + ox*12 + o
        int o = u % 12, ox = (u/12) % 3, oy = u/36;
        float s = 0.f;
        for (int kh = 0; kh < 5; ++kh) {
            int iy = oy*3 - 1 + kh;
            if (iy < 0 || iy > 8) continue;
            for (int kw = 0; kw < 5; ++kw) {
                int ix = ox*3 - 1 + kw;
                if (ix < 0 || ix > 8) continue;
                for (int i = 0; i < 3; ++i)
                    s += sin_[(iy*9+ix)*3 + i] * d1_k[((kh*5+kw)*3 + i)*12 + o];
            }
        }
        z1[u] = LEAKY(BN2 * s);
    }
    __syncthreads();

    // im = leaky(conv1x1(inp / colmax)) ; layout (b,ch,81)
    if (t < 243) {
        int o = t / 81, p = t % 81;
        int c = p % 9;
        float s = x1_b[o];
        for (int i = 0; i < 3; ++i)
            s += (sin_[p*3+i] / cm[c*3+i]) * x1_k[i*3 + o];
        ws[IM_OFF + (b*3 + o)*81 + p] = LEAKY(s);
    }
    __syncthreads();

    // d2 conv: 3x3x12 -> 1x1x24 (kernel rows/cols 1..3 valid)
    if (t < 24) {
        float s = 0.f;
        for (int kh = 1; kh < 4; ++kh)
            for (int kw = 1; kw < 4; ++kw)
                for (int i = 0; i < 12; ++i)
                    s += z1[((kh-1)*3 + (kw-1))*12 + i] * d2_k[((kh*5+kw)*12 + i)*24 + t];
        z2[t] = LEAKY(BN * s);
    }
    __syncthreads();
    if (t < 24) {
        float s = h1_b[t];
        for (int i = 0; i < 24; ++i) s += z2[i] * h1_w[i*24 + t];
        v1[t] = s;
    }
    __syncthreads();
    if (t < 12) {
        float s = h2_b[t];
        for (int i = 0; i < 24; ++i) s += v1[i] * h2_w[i*12 + t];
        v2[t] = s;
    }
    __syncthreads();
    if (t == 0) {
        float s = h3_b[0];
        for (int i = 0; i < 12; ++i) s += v2[i] * h3_w[i];
        ws[LAM_OFF + b] = 0.01f / (1.f + expf(-s));   // 0.1*sigmoid * 0.1
    }

    // y branch: cat = [y1(32) | y2(32)] per position
    for (int u = t; u < 5184; u += 256) {
        int pos = u / 64, i = u % 64;
        int r = pos / 9, c = pos % 9;
        float s;
        if (i < 32) {
            s = y17_b[i];
            for (int kw = 0; kw < 7; ++kw) {
                int cc = c - 3 + kw;
                if (cc < 0 || cc > 8) continue;
                for (int ii = 0; ii < 3; ++ii)
                    s += sin_[(r*9+cc)*3 + ii] * y17_k[(kw*3+ii)*32 + i];
            }
        } else {
            int i2 = i - 32;
            s = y71_b[i2];
            for (int kh = 0; kh < 7; ++kh) {
                int rr = r - 3 + kh;
                if (rr < 0 || rr > 8) continue;
                for (int ii = 0; ii < 3; ++ii)
                    s += sin_[(rr*9+c)*3 + ii] * y71_k[(kh*3+ii)*32 + i2];
            }
        }
        cat[pos*64 + i] = s;
    }
    __syncthreads();
    for (int u = t; u < 2592; u += 256) {
        int pos = u / 32, o = u % 32;
        float s = yc_b[o];
        for (int i = 0; i < 64; ++i) s += cat[pos*64 + i] * yc_k[i*32 + o];
        ws[YBR_OFF + (b*81 + pos)*32 + o] = LEAKY(s);
    }
}

// ======================= FISTA =======================
// One block per (b,ch). Thread (j=t%72, grp=t/72) owns col j, rows grp*12..+11
// of the 72x72 y image (432 active of 512). G rows live in REGISTERS (constant
// over 100 iters): Gr[12][9] = per-thread A-phase rows, Gj[9] = row j for Qt,
// GTr[12] = G^T chunk for the S-partial role. LDS holds only per-iteration
// cross-thread traffic (Qt, U, T, P, R), all lane-consecutive / padded
// conflict-free. 5 barriers/iter, every phase >= 432-wide.
__global__ __launch_bounds__(512, 2) void fista_kernel(
    const float* __restrict__ ws, float* __restrict__ cs_out)
{
    __shared__ __align__(16) float Qt[648];      // [a][j]
    __shared__ __align__(16) float U[9*432];     // [a][grp*72+j] V-partials
    __shared__ __align__(16) float T[9*76];      // [a][j] V, padded 76
    __shared__ __align__(16) float P[6*84];      // [seg][a*9+b] S-partials
    __shared__ __align__(16) float R[108];       // [a][b] resid, padded 12

    int t = threadIdx.x;
    int b = blockIdx.x / 3, ch = blockIdx.x % 3;
    const float* g = ws + G_OFF;
    float lam = ws[LAM_OFF + b];

    int j = t % 72, grp = t / 72;
    bool act = t < 432;

    // ---- register preloads (one-time; same-address across lanes -> L1 broadcast)
    float Gr[108];
    if (act) {
#pragma unroll
        for (int s = 0; s < 12; ++s)
#pragma unroll
            for (int a = 0; a < 9; ++a)
                Gr[s*9 + a] = g[(grp*12 + s)*9 + a];
    }
    float Gj[9];
    if (act) {
#pragma unroll
        for (int a = 0; a < 9; ++a) Gj[a] = g[j*9 + a];
    }
    int pa = t / 54, prem = t % 54, pb = prem / 6, pseg = prem % 6;
    float GTr[12];
    if (t < 486) {
#pragma unroll
        for (int r = 0; r < 12; ++r) GTr[r] = g[(pseg*12 + r)*9 + pb];
    }
    float im_ab = 0.f;
    if (t < 81) im_ab = ws[IM_OFF + (b*3 + ch)*81 + t];
    // init R = im (pads zero; P4b never touches pads afterwards)
    if (t < 108) {
        int a = t / 12, c = t % 12;
        R[t] = (c < 9) ? ws[IM_OFF + (b*3 + ch)*81 + a*9 + c] : 0.f;
    }

    float Yv[12], Yl[12];
#pragma unroll
    for (int s = 0; s < 12; ++s) { Yv[s] = 0.f; Yl[s] = 0.f; }
    float tk = 1.f;
    __syncthreads();

    for (int it = 0; it < 100; ++it) {
        // ---- P1: Qt[a][j] = dot(R row a, Gj)  (Gj in regs; R broadcast)
        if (act) {
            const float4* R4 = (const float4*)(R + grp*12);
            float4 r0 = R4[0], r1 = R4[1], r2 = R4[2];
            Qt[grp*72 + j] =
                r0.x*Gj[0] + r0.y*Gj[1] + r0.z*Gj[2] + r0.w*Gj[3]
              + r1.x*Gj[4] + r1.y*Gj[5] + r1.z*Gj[6] + r1.w*Gj[7]
              + r2.x*Gj[8];
        }
        if (t < 216) {
            int a2 = 6 + t/72;
            const float4* R4 = (const float4*)(R + a2*12);
            float4 r0 = R4[0], r1 = R4[1], r2 = R4[2];
            Qt[a2*72 + j] =
                r0.x*Gj[0] + r0.y*Gj[1] + r0.z*Gj[2] + r0.w*Gj[3]
              + r1.x*Gj[4] + r1.y*Gj[5] + r1.z*Gj[6] + r1.w*Gj[7]
              + r2.x*Gj[8];
        }
        __syncthreads();
        float tn = 0.5f*(1.f + sqrtf(1.f + 4.f*tk*tk));
        float cmom = (tk - 1.f) / tn;
        tk = tn;
        // ---- P2: per-element update + V-partials (G rows in regs)
        if (act) {
            float q0 = Qt[0*72+j], q1 = Qt[1*72+j], q2 = Qt[2*72+j],
                  q3 = Qt[3*72+j], q4 = Qt[4*72+j], q5 = Qt[5*72+j],
                  q6 = Qt[6*72+j], q7 = Qt[7*72+j], q8 = Qt[8*72+j];
            float u0=0,u1=0,u2=0,u3=0,u4=0,u5=0,u6=0,u7=0,u8=0;
#pragma unroll
            for (int s = 0; s < 12; ++s) {
                float re = Gr[s*9+0]*q0 + Gr[s*9+1]*q1 + Gr[s*9+2]*q2
                         + Gr[s*9+3]*q3 + Gr[s*9+4]*q4 + Gr[s*9+5]*q5
                         + Gr[s*9+6]*q6 + Gr[s*9+7]*q7 + Gr[s*9+8]*q8;
                float wv = Yv[s] + re;
                float aa = fabsf(wv) - lam;
                float yn = aa > 0.f ? copysignf(aa, wv) : 0.f;
                float yx = yn + cmom*(yn - Yl[s]);
                Yl[s] = yn; Yv[s] = yx;
                u0 += yx*Gr[s*9+0]; u1 += yx*Gr[s*9+1]; u2 += yx*Gr[s*9+2];
                u3 += yx*Gr[s*9+3]; u4 += yx*Gr[s*9+4]; u5 += yx*Gr[s*9+5];
                u6 += yx*Gr[s*9+6]; u7 += yx*Gr[s*9+7]; u8 += yx*Gr[s*9+8];
            }
            U[0*432+t]=u0; U[1*432+t]=u1; U[2*432+t]=u2; U[3*432+t]=u3;
            U[4*432+t]=u4; U[5*432+t]=u5; U[6*432+t]=u6; U[7*432+t]=u7;
            U[8*432+t]=u8;
        }
        if (it == 99) break;
        __syncthreads();
        // ---- P3: T[a][j] = sum_grp U[a][grp*72+j]   (grp-reduce, 648-wide)
        if (act) {
            float s = U[grp*432 + j]       + U[grp*432 + 72 + j]
                    + U[grp*432 + 144 + j] + U[grp*432 + 216 + j]
                    + U[grp*432 + 288 + j] + U[grp*432 + 360 + j];
            T[grp*76 + j] = s;
        }
        if (t < 216) {
            int a2 = 6 + t/72;
            float s = U[a2*432 + j]       + U[a2*432 + 72 + j]
                    + U[a2*432 + 144 + j] + U[a2*432 + 216 + j]
                    + U[a2*432 + 288 + j] + U[a2*432 + 360 + j];
            T[a2*76 + j] = s;
        }
        __syncthreads();
        // ---- P4a: S-partials over 12-j segments (G^T chunk in regs)
        if (t < 486) {
            const float4* T4 = (const float4*)(T + pa*76 + pseg*12);
            float4 t0 = T4[0], t1 = T4[1], t2 = T4[2];
            P[pseg*84 + pa*9 + pb] =
                t0.x*GTr[0] + t0.y*GTr[1] + t0.z*GTr[2] + t0.w*GTr[3]
              + t1.x*GTr[4] + t1.y*GTr[5] + t1.z*GTr[6] + t1.w*GTr[7]
              + t2.x*GTr[8] + t2.y*GTr[9] + t2.z*GTr[10]+ t2.w*GTr[11];
        }
        __syncthreads();
        // ---- P4b: S-final + residual
        if (t < 81) {
            float s = P[t] + P[84+t] + P[168+t] + P[252+t] + P[336+t] + P[420+t];
            R[(t/9)*12 + (t%9)] = im_ab - s;
        }
        __syncthreads();
    }
    if (act) {
#pragma unroll
        for (int s = 0; s < 12; ++s) {
            int i = grp*12 + s;
            cs_out[(size_t)(b*5184 + i*72 + j)*3 + ch] = Yl[s];
        }
    }
}

// ======================= post convs =======================
__global__ __launch_bounds__(256) void c51_kernel(
    const float* __restrict__ cs, const float* __restrict__ k,
    const float* __restrict__ bias, float* __restrict__ out)
{
    int id = blockIdx.x*256 + threadIdx.x;
    if (id >= 32*36*36*16) return;
    int o = id & 15; int rest = id >> 4;
    int ox = rest % 36; rest /= 36; int oy = rest % 36; int b = rest / 36;
    float s = bias[o];
    int ix = ox*2;
    for (int kh = 0; kh < 5; ++kh) {
        int iy = oy*2 - 1 + kh;
        if (iy < 0 || iy >= 72) continue;
        const float* p = cs + ((size_t)(b*72 + iy)*72 + ix)*3;
        const float* kk = k + kh*48 + o;
        s += p[0]*kk[0] + p[1]*kk[16] + p[2]*kk[32];
    }
    out[id] = s;
}

__global__ __launch_bounds__(256) void c15_kernel(
    const float* __restrict__ x1, const float* __restrict__ k,
    const float* __restrict__ bias, float* __restrict__ out)
{
    int id = blockIdx.x*256 + threadIdx.x;
    if (id >= 32*18*18*32) return;
    int o = id & 31; int rest = id >> 5;
    int ox = rest % 18; rest /= 18; int oy = rest % 18; int b = rest / 18;
    float s = bias[o];
    int iy = oy*2;
    for (int kw = 0; kw < 5; ++kw) {
        int ix = ox*2 - 1 + kw;
        if (ix < 0 || ix >= 36) continue;
        const float* p = x1 + ((size_t)(b*36 + iy)*36 + ix)*16;
        const float* kk = k + kw*512 + o;
        for (int i = 0; i < 16; ++i) s += p[i]*kk[i*32];
    }
    out[id] = s;
}

__global__ __launch_bounds__(256) void c55_kernel(
    const float* __restrict__ x2, const float* __restrict__ k,
    const float* __restrict__ bias, float* __restrict__ out)
{
    int id = blockIdx.x*256 + threadIdx.x;
    if (id >= 32*9*9*64) return;
    int o = id & 63; int rest = id >> 6;
    int ox = rest % 9; rest /= 9; int oy = rest % 9; int b = rest / 9;
    float s = bias[o];
    for (int kh = 0; kh < 5; ++kh) {
        int iy = oy*2 - 1 + kh;
        if (iy < 0 || iy >= 18) continue;
        for (int kw = 0; kw < 5; ++kw) {
            int ix = ox*2 - 1 + kw;
            if (ix < 0 || ix >= 18) continue;
            const float* p = x2 + ((size_t)(b*18 + iy)*18 + ix)*32;
            const float* kk = k + (kh*5+kw)*2048 + o;
            for (int i = 0; i < 32; ++i) s += p[i]*kk[i*64];
        }
    }
    out[id] = s;
}

__global__ __launch_bounds__(256) void out_kernel(
    const float* __restrict__ ws, const float* __restrict__ x2_k,
    const float* __restrict__ x2_b, float* __restrict__ out)
{
    int id = blockIdx.x*256 + threadIdx.x;
    if (id >= OUT0) return;
    int q = id % 41; int rest = id / 41;
    int cc = rest % 9; rest /= 9; int r = rest % 9; int b = rest / 9;
    float val;
    if (q == 0) {
        val = ws[WB_OFF + b*81 + r*9 + cc];
    } else if (q <= 8) {
        int o = q - 1;
        const float* p = ws + X3_OFF + ((size_t)(b*9 + r)*9 + cc)*64;
        float s = x2_b[o];
        for (int i = 0; i < 64; ++i) s += p[i]*x2_k[i*8 + o];
        val = LEAKY(s);
    } else {
        val = ws[YBR_OFF + ((size_t)(b*81 + r*9 + cc))*32 + (q - 9)];
    }
    out[id] = val;
}

// ======================= launch =======================
extern "C" void kernel_launch(void* const* d_in, const int* in_sizes, int n_in,
                              void* d_out, int out_size, void* d_ws, size_t ws_size,
                              hipStream_t stream) {
    const float* inp   = (const float*)d_in[0];
    const float* mat   = (const float*)d_in[1];
    const float* w1_k  = (const float*)d_in[2];
    const float* w1_b  = (const float*)d_in[3];
    const float* x1_k  = (const float*)d_in[4];
    const float* x1_b  = (const float*)d_in[5];
    const float* c51_k = (const float*)d_in[6];
    const float* c51_b = (const float*)d_in[7];
    const float* c15_k = (const float*)d_in[8];
    const float* c15_b = (const float*)d_in[9];
    const float* c55_k = (const float*)d_in[10];
    const float* c55_b = (const float*)d_in[11];
    const float* x2_k  = (const float*)d_in[12];
    const float* x2_b  = (const float*)d_in[13];
    const float* y17_k = (const float*)d_in[14];
    const float* y17_b = (const float*)d_in[15];
    const float* y71_k = (const float*)d_in[16];
    const float* y71_b = (const float*)d_in[17];
    const float* yc_k  = (const float*)d_in[18];
    const float* yc_b  = (const float*)d_in[19];
    const float* d1_k  = (const float*)d_in[20];
    const float* d2_k  = (const float*)d_in[21];
    const float* h1_w  = (const float*)d_in[22];
    const float* h1_b  = (const float*)d_in[23];
    const float* h2_w  = (const float*)d_in[24];
    const float* h2_b  = (const float*)d_in[25];
    const float* h3_w  = (const float*)d_in[26];
    const float* h3_b  = (const float*)d_in[27];

    float* ws  = (float*)d_ws;
    float* out = (float*)d_out;
    float* cs  = out + OUT0;

    hipLaunchKernelGGL(prep_kernel, dim3(33), dim3(256), 0, stream,
        inp, mat, w1_k, w1_b, x1_k, x1_b, y17_k, y17_b, y71_k, y71_b,
        yc_k, yc_b, d1_k, d2_k, h1_w, h1_b, h2_w, h2_b, h3_w, h3_b, ws);
    hipLaunchKernelGGL(fista_kernel, dim3(96), dim3(512), 0, stream, ws, cs);
    hipLaunchKernelGGL(c51_kernel, dim3(2592), dim3(256), 0, stream, cs, c51_k, c51_b, ws + X1_OFF);
    hipLaunchKernelGGL(c15_kernel, dim3(1296), dim3(256), 0, stream, ws + X1_OFF, c15_k, c15_b, ws + X2_OFF);
    hipLaunchKernelGGL(c55_kernel, dim3(648), dim3(256), 0, stream, ws + X2_OFF, c55_k, c55_b, ws + X3_OFF);
    hipLaunchKernelGGL(out_kernel, dim3(416), dim3(256), 0, stream, ws, x2_k, x2_b, out);
}